// Round 8
// baseline (251.065 us; speedup 1.0000x reference)
//
#include <hip/hip_runtime.h>

#define B_ 2
#define S_ 2048
#define H_ 1024
#define NH 16
#define HD 64
#define LN_EPS 1e-5f

typedef unsigned short u16;
typedef unsigned int u32;
typedef __attribute__((ext_vector_type(8))) short bf16x8;
typedef __attribute__((ext_vector_type(4))) float f32x4;
typedef __attribute__((ext_vector_type(16))) float f32x16;
typedef __attribute__((ext_vector_type(4))) u32 u32x4;
typedef __attribute__((ext_vector_type(4))) u16 u16x4;

__device__ __forceinline__ u16 f2bf(float f) {
  u32 u = __float_as_uint(f);
  u32 r = (u + 0x7FFFu + ((u >> 16) & 1u)) >> 16;
  return (u16)r;
}
__device__ __forceinline__ float bflo(u32 w) { return __uint_as_float(w << 16); }
__device__ __forceinline__ float bfhi(u32 w) { return __uint_as_float(w & 0xffff0000u); }

// async global->LDS, 16B per lane
__device__ __forceinline__ void gload_lds16(const void* g, void* l) {
  __builtin_amdgcn_global_load_lds(
      (const __attribute__((address_space(1))) void*)(uintptr_t)g,
      (__attribute__((address_space(3))) void*)(uintptr_t)l, 16, 0, 0);
}

// ---------------- f32 -> bf16 conversion ----------------
__global__ __launch_bounds__(256) void k_cvt(const float* __restrict__ in,
                                             u16* __restrict__ out, int n4) {
  int i = blockIdx.x * 256 + threadIdx.x;
  if (i >= n4) return;
  f32x4 v = ((const f32x4*)in)[i];
  u16x4 o = { f2bf(v[0]), f2bf(v[1]), f2bf(v[2]), f2bf(v[3]) };
  ((u16x4*)out)[i] = o;
}

// ---------------- pack 3 bias vectors ----------------
__global__ __launch_bounds__(256) void k_pack3(const float* __restrict__ a,
                                               const float* __restrict__ b,
                                               const float* __restrict__ c,
                                               float* __restrict__ o) {
  int i = blockIdx.x * 256 + threadIdx.x;
  if (i >= 3 * H_) return;
  o[i] = (i < H_) ? a[i] : (i < 2 * H_ ? b[i - H_] : c[i - 2 * H_]);
}

// ============ 256x256 8-phase GEMM (airtight schedule, round-7 verified) ============
template<int RELU, int F32OUT, int BF16OUT, int BIAS>
__global__ __launch_bounds__(512, 2) void k_gemm8(const u16* __restrict__ A,
                                                  const u16* __restrict__ W,
                                                  const float* __restrict__ bias,
                                                  float* __restrict__ outf,
                                                  u16* __restrict__ outb,
                                                  int M, int N, int lda, int ldb,
                                                  int Kc, int tilesM) {
  extern __shared__ u16 lds[];
  const int tid = threadIdx.x, lane = tid & 63, wid = tid >> 6;
  const int wr = wid >> 2, wc = wid & 3;
  const int lr = lane & 15, lk = lane >> 4;

  const int nwg = gridDim.x;
  const int bid = blockIdx.x;
  const int lid = (bid & 7) * (nwg >> 3) + (bid >> 3);
  const int ty = lid % tilesM;
  const int txz = lid / tilesM;
  const int tilesN = N >> 8;
  const int tx = txz % tilesN;
  const int kz = txz / tilesN;
  const int row0 = ty << 8, col0 = tx << 8;
  A += (size_t)kz * Kc;
  W += (size_t)kz * Kc;
  const size_t outoff = (size_t)kz * M * N;

  const int NT = Kc >> 6;

  f32x4 acc[8][4];
#pragma unroll
  for (int i = 0; i < 8; ++i)
#pragma unroll
    for (int j = 0; j < 4; ++j) acc[i][j] = (f32x4){0.f, 0.f, 0.f, 0.f};

  const int srow = tid >> 3;
  const int csw8 = ((tid & 7) ^ (srow & 7)) << 3;

  auto stage_ht = [&](int ht) {
    const int t = ht >> 2, sel = ht & 3;
    const int mat = (sel < 2) ? 1 : 0;
    const int hh = sel & 1;
    const u16* g = mat ? W : A;
    const int ld = mat ? ldb : lda;
    const int b0 = mat ? col0 : row0;
    const int kt = t << 6;
    u16* dst = lds + ((t & 1) << 15) + (mat << 14) + (hh << 13) + tid * 8;
#pragma unroll
    for (int j = 0; j < 2; ++j) {
      const int r = (hh << 7) + (j << 6) + srow;
      gload_lds16(g + (size_t)(b0 + r) * ld + kt + csw8, dst + (j << 12));
    }
  };

  union UU { u32x4 u; bf16x8 b; };
  auto ldvec = [&](const u16* base, int r, int c) -> bf16x8 {
    UU x;
    x.u = *(const u32x4*)(base + r * 64 + ((c ^ (r & 7)) << 3));
    return x.b;
  };

#pragma unroll
  for (int i = 0; i < 4; ++i) stage_ht(i);
  asm volatile("s_waitcnt vmcnt(0)" ::: "memory");
  __builtin_amdgcn_s_barrier();

  for (int t = 0; t < NT; ++t) {
    const u16* SA = lds + ((t & 1) << 15);
    const u16* SB = SA + 16384;
#pragma unroll
    for (int ph = 0; ph < 4; ++ph) {
      const int mh = ph >> 1, ks = ph & 1;
      const int c = (ks << 2) + lk;
      bf16x8 bb[4], aa[4];
#pragma unroll
      for (int ni = 0; ni < 4; ++ni)
        bb[ni] = ldvec(SB, (wc << 6) + (ni << 4) + lr, c);
#pragma unroll
      for (int mi = 0; mi < 4; ++mi)
        aa[mi] = ldvec(SA, (wr << 7) + (mh << 6) + (mi << 4) + lr, c);
      if (t + 1 < NT && ph < 2) {
        stage_ht(4 * (t + 1) + 2 * ph);
        stage_ht(4 * (t + 1) + 2 * ph + 1);
      }
      __builtin_amdgcn_s_barrier();
      __builtin_amdgcn_s_setprio(1);
#pragma unroll
      for (int mi = 0; mi < 4; ++mi)
#pragma unroll
        for (int ni = 0; ni < 4; ++ni)
          acc[(mh << 2) + mi][ni] = __builtin_amdgcn_mfma_f32_16x16x32_bf16(
              aa[mi], bb[ni], acc[(mh << 2) + mi][ni], 0, 0, 0);
      __builtin_amdgcn_s_setprio(0);
      if (ph == 3)
        asm volatile("s_waitcnt vmcnt(0)" ::: "memory");
      __builtin_amdgcn_s_barrier();
    }
  }

  float bs[4] = {0.f, 0.f, 0.f, 0.f};
  if (BIAS) {
#pragma unroll
    for (int ni = 0; ni < 4; ++ni)
      bs[ni] = bias[col0 + (wc << 6) + (ni << 4) + lr];
  }
#pragma unroll
  for (int mi = 0; mi < 8; ++mi) {
#pragma unroll
    for (int ni = 0; ni < 4; ++ni) {
#pragma unroll
      for (int r = 0; r < 4; ++r) {
        int row = row0 + (wr << 7) + (mi << 4) + (lk << 2) + r;
        int col = col0 + (wc << 6) + (ni << 4) + lr;
        float v = acc[mi][ni][r] + bs[ni];
        if (RELU) v = fmaxf(v, 0.f);
        if (F32OUT) outf[outoff + (size_t)row * N + col] = v;
        if (BF16OUT) outb[outoff + (size_t)row * N + col] = f2bf(v);
      }
    }
  }
}

// ---------------- V transpose: QKV[(b,s)][2048+h*64+d] -> Vt[bh][d][s] ----------------
__global__ __launch_bounds__(256) void k_vt(const u16* __restrict__ QKV,
                                            u16* __restrict__ vt) {
  __shared__ u16 T[64 * 64];
  const int tid = threadIdx.x;
  const int s0 = blockIdx.x * 64;
  const int bh = blockIdx.y;
  const int b = bh >> 4, h = bh & 15;
#pragma unroll
  for (int p = 0; p < 2; ++p) {
    int id = p * 256 + tid;
    int r = id >> 3, c = id & 7;
    u32x4 v = *(const u32x4*)(QKV + (size_t)(b * S_ + s0 + r) * 3072 + 2048 + h * 64 + c * 8);
    int sw = (r ^ (r >> 3)) & 7;
    *(u32x4*)(T + r * 64 + ((c ^ sw) << 3)) = v;
  }
  __syncthreads();
#pragma unroll
  for (int p = 0; p < 2; ++p) {
    int id = p * 256 + tid;
    int d = id >> 3, cs = id & 7;
    u16 tmp[8];
#pragma unroll
    for (int k = 0; k < 8; ++k) {
      int r = cs * 8 + k;
      int sw = (r ^ (r >> 3)) & 7;
      tmp[k] = T[r * 64 + ((((d >> 3) ^ sw)) << 3) + (d & 7)];
    }
    *(u32x4*)(vt + ((size_t)bh * 64 + d) * 2048 + s0 + cs * 8) = *(const u32x4*)tmp;
  }
}

// ======== MFMA flash attention, swapped-QK^T 32x32, async double-buffered K/V ========
// 2 LDS slots x (K 64x64 | V^T 64x64) staged via global_load_lds with
// pre-swizzled source (chunk c of row r holds global chunk c^(r&7));
// tile kv+1's 4 loads issued BEFORE computing tile kv; single vmcnt(0)+barrier
// per tile (loads land under QK^T+softmax+PV). Epilogue reuses LDS for the
// O^T transpose.
__global__ __launch_bounds__(256) void k_attn_mfma(const u16* __restrict__ QKV,
                                                   const u16* __restrict__ Vt,
                                                   u16* __restrict__ mid) {
  __shared__ u16 lds[16384];  // 2 slots x 8192 (K 4096 | V 4096); epilogue Ow 9216
  const int tid = threadIdx.x, lane = tid & 63, wid = tid >> 6;
  const int lq = lane & 31, lh = lane >> 5;
  const int qb = (S_ / 128 - 1) - blockIdx.x;  // heavy blocks first
  const int bh = blockIdx.y;
  const int b = bh >> 4, h = bh & 15;
  const int q0w = qb * 128 + wid * 32;
  const int qg = q0w + lq;

  // staging geometry: r = tid>>3 (row 0..31, +32 second group), c = tid&7
  const int srow = tid >> 3, sc = tid & 7;
  const int ssw = ((sc ^ (srow & 7)) << 3);  // pre-swizzled chunk (r and r+32 share r&7)
  const u16* srcK = QKV + (size_t)b * S_ * 3072 + 1024 + h * 64;
  const u16* srcV = Vt + (size_t)bh * 64 * 2048;

  auto stage = [&](int kv, int slot) {
    u16* dK = lds + slot * 8192 + tid * 8;
    u16* dV = dK + 4096;
    const u16* sk = srcK + (size_t)(kv * 64 + srow) * 3072 + ssw;
    const u16* sv = srcV + (size_t)srow * 2048 + kv * 64 + ssw;
    gload_lds16(sk, dK);
    gload_lds16(sk + (size_t)32 * 3072, dK + 2048);
    gload_lds16(sv, dV);
    gload_lds16(sv + (size_t)32 * 2048, dV + 2048);
  };

  // ---- Q fragments (x 1/sqrt(64)) ----
  union U { u32x4 u; bf16x8 b; };
  U qf[4];
#pragma unroll
  for (int ks = 0; ks < 4; ++ks) {
    const size_t off = (size_t)(b * S_ + qg) * 3072 + h * HD + ks * 16 + lh * 8;
    u32x4 u = *(const u32x4*)(QKV + off);
    u32x4 s;
#pragma unroll
    for (int t = 0; t < 4; ++t) {
      u32 lo = (u32)f2bf(bflo(u[t]) * 0.125f);
      u32 hi = (u32)f2bf(bfhi(u[t]) * 0.125f);
      s[t] = lo | (hi << 16);
    }
    qf[ks].u = s;
  }

  float m = -1e30f, l = 0.f;
  f32x16 acc[2];
#pragma unroll
  for (int mo = 0; mo < 2; ++mo)
#pragma unroll
    for (int r = 0; r < 16; ++r) acc[mo][r] = 0.f;

  const int nt = qb * 2 + 2;

  stage(0, 0);
  asm volatile("s_waitcnt vmcnt(0)" ::: "memory");
  __builtin_amdgcn_s_barrier();

  for (int kv = 0; kv < nt; ++kv) {
    const int kv0 = kv * 64;
    const int cur = kv & 1;
    if (kv + 1 < nt) stage(kv + 1, cur ^ 1);  // issue early; lands under compute

    if (kv0 <= q0w + 31) {
      const u16* Ks = lds + cur * 8192;
      const u16* Vs = Ks + 4096;

      // ---- S^T = K @ Q^T ----
      f32x16 sf[2];
#pragma unroll
      for (int nf = 0; nf < 2; ++nf)
#pragma unroll
        for (int r = 0; r < 16; ++r) sf[nf][r] = 0.f;
#pragma unroll
      for (int ks = 0; ks < 4; ++ks) {
#pragma unroll
        for (int nf = 0; nf < 2; ++nf) {
          int r = nf * 32 + lq;
          int c = ks * 2 + lh;
          U kf;
          kf.u = *(const u32x4*)(Ks + r * 64 + ((c ^ (r & 7)) << 3));
          sf[nf] = __builtin_amdgcn_mfma_f32_32x32x16_bf16(kf.b, qf[ks].b, sf[nf], 0, 0, 0);
        }
      }

      // ---- causal mask (boundary tiles) ----
      if (kv0 + 63 > q0w) {
#pragma unroll
        for (int nf = 0; nf < 2; ++nf)
#pragma unroll
          for (int r = 0; r < 16; ++r) {
            int kvg = kv0 + nf * 32 + (r & 3) + 8 * (r >> 2) + 4 * lh;
            if (kvg > qg) sf[nf][r] = -1e30f;
          }
      }

      // ---- in-register online softmax ----
      float tm = sf[0][0];
#pragma unroll
      for (int r = 1; r < 16; ++r) tm = fmaxf(tm, sf[0][r]);
#pragma unroll
      for (int r = 0; r < 16; ++r) tm = fmaxf(tm, sf[1][r]);
      tm = fmaxf(tm, __shfl_xor(tm, 32));
      const float mn = fmaxf(m, tm);
      const float corr = __expf(m - mn);
      m = mn;
      float rs = 0.f;
#pragma unroll
      for (int nf = 0; nf < 2; ++nf)
#pragma unroll
        for (int r = 0; r < 16; ++r) {
          float p = __expf(sf[nf][r] - mn);
          sf[nf][r] = p;
          rs += p;
        }
      rs += __shfl_xor(rs, 32);
      l = l * corr + rs;
#pragma unroll
      for (int mo = 0; mo < 2; ++mo)
#pragma unroll
        for (int r = 0; r < 16; ++r) acc[mo][r] *= corr;

      // ---- P -> packed bf16, O^T += V^T @ P^T ----
      u32 q32[2][8];
#pragma unroll
      for (int nf = 0; nf < 2; ++nf)
#pragma unroll
        for (int i = 0; i < 8; ++i)
          asm("v_cvt_pk_bf16_f32 %0, %1, %2"
              : "=v"(q32[nf][i]) : "v"(sf[nf][2 * i]), "v"(sf[nf][2 * i + 1]));

#pragma unroll
      for (int s = 0; s < 4; ++s) {
        const int nfp = s >> 1, sg = s & 1;
        u32 x = q32[nfp][4 * sg + 0];
        u32 y = q32[nfp][4 * sg + 1];
        u32 z = q32[nfp][4 * sg + 2];
        u32 w = q32[nfp][4 * sg + 3];
        asm("v_permlane32_swap_b32 %0, %1" : "+v"(x), "+v"(z));
        asm("v_permlane32_swap_b32 %0, %1" : "+v"(y), "+v"(w));
        U pb;
        pb.u = (u32x4){x, y, z, w};
#pragma unroll
        for (int mo = 0; mo < 2; ++mo) {
          int r = mo * 32 + lq;
          int c = s * 2 + lh;
          U vv;
          vv.u = *(const u32x4*)(Vs + r * 64 + ((c ^ (r & 7)) << 3));
          acc[mo] = __builtin_amdgcn_mfma_f32_32x32x16_bf16(vv.b, pb.b, acc[mo], 0, 0, 0);
        }
      }
    }

    asm volatile("s_waitcnt vmcnt(0)" ::: "memory");  // next tile fully in LDS
    __builtin_amdgcn_s_barrier();
  }

  // ---- epilogue: O^T/l -> LDS transpose -> coalesced store ----
  u16* Ow = lds + wid * (32 * 72);
  const float inv = 1.f / l;
#pragma unroll
  for (int mo = 0; mo < 2; ++mo)
#pragma unroll
    for (int r = 0; r < 16; ++r) {
      int d = mo * 32 + (r & 3) + 8 * (r >> 2) + 4 * lh;
      Ow[lq * 72 + d] = f2bf(acc[mo][r] * inv);
    }
  __asm__ volatile("" ::: "memory");
#pragma unroll
  for (int r4 = 0; r4 < 4; ++r4) {
    int ql = r4 * 8 + (lane >> 3);
    int c = lane & 7;
    u32x4 v = *(const u32x4*)(Ow + ql * 72 + c * 8);
    *(u32x4*)(mid + (size_t)(b * S_ + q0w + ql) * H_ + h * HD + c * 8) = v;
  }
}

// ------- fused residual + split-K reduce + LayerNorm -------
// t = a + bd + sum_{z<NZ} P[z]; out = LN(t)*g + bb  (optional bf16 copy)
template<int BF16OUT, int NZ>
__global__ __launch_bounds__(256) void k_lnr(const float* __restrict__ a,
                                             const u16* __restrict__ P,
                                             const float* __restrict__ bd,
                                             const float* __restrict__ g,
                                             const float* __restrict__ bb,
                                             float* __restrict__ outf,
                                             u16* __restrict__ outb) {
  __shared__ float red[8];
  const int row = blockIdx.x, tid = threadIdx.x;
  const size_t base = (size_t)row * H_ + tid * 4;
  f32x4 t = *(const f32x4*)(a + base);
  f32x4 vb = *(const f32x4*)(bd + tid * 4);
  t += vb;
#pragma unroll
  for (int z = 0; z < NZ; ++z) {
    u16x4 p = *(const u16x4*)(P + (size_t)z * ((size_t)B_ * S_ * H_) + base);
#pragma unroll
    for (int e = 0; e < 4; ++e) t[e] += __uint_as_float((u32)p[e] << 16);
  }
  float sum = t[0] + t[1] + t[2] + t[3];
#pragma unroll
  for (int msk = 32; msk >= 1; msk >>= 1) sum += __shfl_xor(sum, msk, 64);
  if ((tid & 63) == 0) red[tid >> 6] = sum;
  __syncthreads();
  float mu = (red[0] + red[1] + red[2] + red[3]) * (1.f / H_);
  f32x4 d = t - mu;
  float sq = d[0] * d[0] + d[1] * d[1] + d[2] * d[2] + d[3] * d[3];
#pragma unroll
  for (int msk = 32; msk >= 1; msk >>= 1) sq += __shfl_xor(sq, msk, 64);
  if ((tid & 63) == 0) red[4 + (tid >> 6)] = sq;
  __syncthreads();
  float var = (red[4] + red[5] + red[6] + red[7]) * (1.f / H_);
  float rs = rsqrtf(var + LN_EPS);
  f32x4 gg = *(const f32x4*)(g + tid * 4);
  f32x4 bv = *(const f32x4*)(bb + tid * 4);
  f32x4 o = d * rs * gg + bv;
  *(f32x4*)(outf + base) = o;
  if (BF16OUT) {
    u16x4 ob = { f2bf(o[0]), f2bf(o[1]), f2bf(o[2]), f2bf(o[3]) };
    *(u16x4*)(outb + base) = ob;
  }
}

// ---------------- host launcher ----------------
extern "C" void kernel_launch(void* const* d_in, const int* in_sizes, int n_in,
                              void* d_out, int out_size, void* d_ws, size_t ws_size,
                              hipStream_t stream) {
  const float* X   = (const float*)d_in[0];
  const float* Wq  = (const float*)d_in[1];
  const float* bq  = (const float*)d_in[2];
  const float* Wk  = (const float*)d_in[3];
  const float* bk  = (const float*)d_in[4];
  const float* Wv  = (const float*)d_in[5];
  const float* bv  = (const float*)d_in[6];
  const float* Wo  = (const float*)d_in[7];
  const float* bo  = (const float*)d_in[8];
  const float* g1  = (const float*)d_in[9];
  const float* b1  = (const float*)d_in[10];
  const float* Wup = (const float*)d_in[11];
  const float* bup = (const float*)d_in[12];
  const float* Wdn = (const float*)d_in[13];
  const float* bdn = (const float*)d_in[14];
  const float* g2  = (const float*)d_in[15];
  const float* b2  = (const float*)d_in[16];
  float* out = (float*)d_out;

  const size_t MS = (size_t)B_ * S_;   // 4096
  const size_t nX = MS * H_;           // 4,194,304

  char* ws = (char*)d_ws;
  size_t off = 0;
  auto alloc = [&](size_t bytes) {
    char* p = ws + off;
    off += (bytes + 255) & ~(size_t)255;
    return p;
  };
  u16* Xb    = (u16*)alloc(nX * 2);                    // 8MB   (h alias start)
  u16* Wqkv  = (u16*)alloc((size_t)3 * H_ * H_ * 2);   // 6MB
  u16* Wob   = (u16*)alloc((size_t)H_ * H_ * 2);       // 2MB   (h = 16MB over these 3)
  u16* Wupb  = (u16*)alloc((size_t)4 * H_ * H_ * 2);   // 8MB
  u16* Wdnb  = (u16*)alloc((size_t)4 * H_ * H_ * 2);   // 8MB
  float* bqkv = (float*)alloc(3 * H_ * 4);             // 12KB
  u16* QKVb  = (u16*)alloc(nX * 3 * 2);                // 24MB  (upb alias start)
  u16* midb  = (u16*)alloc(nX * 2);                    // 8MB
  u16* Pbuf  = (u16*)alloc(nX * 4 * 2);                // 32MB: vtb / WoP / hb / P
  // aliases (producer strictly after old consumers in stream order):
  float* h   = (float*)Xb;        // 16MB f32 (Xb+Wqkv+Wob dead after QKV/Wo GEMMs)
  u16* upb   = QKVb;              // 32MB (QKVb dead after attn, midb after Wo)
  u16* vtb   = Pbuf;              // 8MB  (dead after attn)
  u16* WoP   = Pbuf;              // 2 x 8MB Wo split-K partials (over dead vtb)
  u16* hb    = Pbuf + nX * 2;     // 8MB bf16 h at [16,24)MB (WoP ends at 16MB)
  u16* P     = Pbuf;              // 4 x 8MB down partials (WoP+hb dead by then)

  dim3 blk(256);

  k_cvt<<<dim3(4096), blk, 0, stream>>>(X, Xb, (int)(nX / 4));
  k_cvt<<<dim3(1024), blk, 0, stream>>>(Wq, Wqkv, H_ * H_ / 4);
  k_cvt<<<dim3(1024), blk, 0, stream>>>(Wk, Wqkv + (size_t)H_ * H_, H_ * H_ / 4);
  k_cvt<<<dim3(1024), blk, 0, stream>>>(Wv, Wqkv + (size_t)2 * H_ * H_, H_ * H_ / 4);
  k_cvt<<<dim3(1024), blk, 0, stream>>>(Wo, Wob, H_ * H_ / 4);
  k_cvt<<<dim3(4096), blk, 0, stream>>>(Wup, Wupb, 4 * H_ * H_ / 4);
  k_cvt<<<dim3(4096), blk, 0, stream>>>(Wdn, Wdnb, 4 * H_ * H_ / 4);
  k_pack3<<<dim3(12), blk, 0, stream>>>(bq, bk, bv, bqkv);

  // fused QKV projection [4096,3072]: grid 16*12 = 192
  k_gemm8<0, 0, 1, 1><<<dim3(16 * 12), dim3(512), 131072, stream>>>(
      Xb, Wqkv, bqkv, nullptr, QKVb, (int)MS, 3 * H_, H_, H_, H_, 16);

  k_vt<<<dim3(S_ / 64, B_ * NH), blk, 0, stream>>>(QKVb, vtb);

  // causal MFMA flash attention (async double-buffered K/V)
  k_attn_mfma<<<dim3(S_ / 128, B_ * NH), blk, 0, stream>>>(QKVb, vtb, midb);

  // output projection split-K=2, bf16 partials: grid 16*4*2 = 128
  k_gemm8<0, 0, 1, 0><<<dim3(16 * 4 * 2), dim3(512), 131072, stream>>>(
      midb, Wob, nullptr, nullptr, WoP, (int)MS, H_, H_, H_, 512, 16);

  // LN1 + Wo-reduce: h = LN(X + sum WoP + bo), bf16 copy hb
  k_lnr<1, 2><<<dim3(MS), blk, 0, stream>>>(X, WoP, bo, g1, b1, h, hb);

  // MLP up [4096,4096] ReLU: grid 16*16 = 256
  k_gemm8<1, 0, 1, 1><<<dim3(16 * 16), dim3(512), 131072, stream>>>(
      hb, Wupb, bup, nullptr, upb, (int)MS, 4 * H_, H_, H_, H_, 16);

  // MLP down split-K=4, bf16 partials: grid 16*4*4 = 256
  k_gemm8<0, 0, 1, 0><<<dim3(16 * 4 * 4), dim3(512), 131072, stream>>>(
      upb, Wdnb, nullptr, nullptr, P, (int)MS, H_, 4 * H_, 4 * H_, H_, 16);

  // LN2 + down-reduce -> out
  k_lnr<0, 4><<<dim3(MS), blk, 0, stream>>>(h, P, bdn, g2, b2, out, nullptr);
}

// Round 9
// 231.255 us; speedup vs baseline: 1.0857x; 1.0857x over previous
//
#include <hip/hip_runtime.h>

#define B_ 2
#define S_ 2048
#define H_ 1024
#define NH 16
#define HD 64
#define LN_EPS 1e-5f

typedef unsigned short u16;
typedef unsigned int u32;
typedef __attribute__((ext_vector_type(8))) short bf16x8;
typedef __attribute__((ext_vector_type(4))) float f32x4;
typedef __attribute__((ext_vector_type(16))) float f32x16;
typedef __attribute__((ext_vector_type(4))) u32 u32x4;
typedef __attribute__((ext_vector_type(4))) u16 u16x4;

__device__ __forceinline__ u16 f2bf(float f) {
  u32 u = __float_as_uint(f);
  u32 r = (u + 0x7FFFu + ((u >> 16) & 1u)) >> 16;
  return (u16)r;
}
__device__ __forceinline__ float bflo(u32 w) { return __uint_as_float(w << 16); }
__device__ __forceinline__ float bfhi(u32 w) { return __uint_as_float(w & 0xffff0000u); }

// async global->LDS, 16B per lane
__device__ __forceinline__ void gload_lds16(const void* g, void* l) {
  __builtin_amdgcn_global_load_lds(
      (const __attribute__((address_space(1))) void*)(uintptr_t)g,
      (__attribute__((address_space(3))) void*)(uintptr_t)l, 16, 0, 0);
}

// ------- fused f32 -> bf16 conversion of all 7 tensors (one launch) -------
// dst layout (contiguous in ws): Xb | Wq | Wk | Wv | Wo | Wup | Wdn
// quad boundaries: 1048576 | +262144 x4 | +1048576 x2  = 4194304 quads total
__global__ __launch_bounds__(256) void k_cvt_all(const float* __restrict__ X,
                                                 const float* __restrict__ Wq,
                                                 const float* __restrict__ Wk,
                                                 const float* __restrict__ Wv,
                                                 const float* __restrict__ Wo,
                                                 const float* __restrict__ Wup,
                                                 const float* __restrict__ Wdn,
                                                 u16* __restrict__ dst) {
  const int i = blockIdx.x * 256 + threadIdx.x;
  const float* s;
  int off;
  if (i < 1048576)      { s = X;   off = 0; }
  else if (i < 1310720) { s = Wq;  off = 1048576; }
  else if (i < 1572864) { s = Wk;  off = 1310720; }
  else if (i < 1835008) { s = Wv;  off = 1572864; }
  else if (i < 2097152) { s = Wo;  off = 1835008; }
  else if (i < 3145728) { s = Wup; off = 2097152; }
  else                  { s = Wdn; off = 3145728; }
  f32x4 v = ((const f32x4*)s)[i - off];
  u16x4 o = { f2bf(v[0]), f2bf(v[1]), f2bf(v[2]), f2bf(v[3]) };
  ((u16x4*)dst)[i] = o;
}

// ---------------- pack 3 bias vectors ----------------
__global__ __launch_bounds__(256) void k_pack3(const float* __restrict__ a,
                                               const float* __restrict__ b,
                                               const float* __restrict__ c,
                                               float* __restrict__ o) {
  int i = blockIdx.x * 256 + threadIdx.x;
  if (i >= 3 * H_) return;
  o[i] = (i < H_) ? a[i] : (i < 2 * H_ ? b[i - H_] : c[i - 2 * H_]);
}

// ============ 256x256 8-phase GEMM (airtight schedule, round-7 verified) ============
template<int RELU, int F32OUT, int BF16OUT, int BIAS>
__global__ __launch_bounds__(512, 2) void k_gemm8(const u16* __restrict__ A,
                                                  const u16* __restrict__ W,
                                                  const float* __restrict__ bias,
                                                  float* __restrict__ outf,
                                                  u16* __restrict__ outb,
                                                  int M, int N, int lda, int ldb,
                                                  int Kc, int tilesM) {
  extern __shared__ u16 lds[];
  const int tid = threadIdx.x, lane = tid & 63, wid = tid >> 6;
  const int wr = wid >> 2, wc = wid & 3;
  const int lr = lane & 15, lk = lane >> 4;

  const int nwg = gridDim.x;
  const int bid = blockIdx.x;
  const int lid = (bid & 7) * (nwg >> 3) + (bid >> 3);
  const int ty = lid % tilesM;
  const int txz = lid / tilesM;
  const int tilesN = N >> 8;
  const int tx = txz % tilesN;
  const int kz = txz / tilesN;
  const int row0 = ty << 8, col0 = tx << 8;
  A += (size_t)kz * Kc;
  W += (size_t)kz * Kc;
  const size_t outoff = (size_t)kz * M * N;

  const int NT = Kc >> 6;

  f32x4 acc[8][4];
#pragma unroll
  for (int i = 0; i < 8; ++i)
#pragma unroll
    for (int j = 0; j < 4; ++j) acc[i][j] = (f32x4){0.f, 0.f, 0.f, 0.f};

  const int srow = tid >> 3;
  const int csw8 = ((tid & 7) ^ (srow & 7)) << 3;

  auto stage_ht = [&](int ht) {
    const int t = ht >> 2, sel = ht & 3;
    const int mat = (sel < 2) ? 1 : 0;
    const int hh = sel & 1;
    const u16* g = mat ? W : A;
    const int ld = mat ? ldb : lda;
    const int b0 = mat ? col0 : row0;
    const int kt = t << 6;
    u16* dst = lds + ((t & 1) << 15) + (mat << 14) + (hh << 13) + tid * 8;
#pragma unroll
    for (int j = 0; j < 2; ++j) {
      const int r = (hh << 7) + (j << 6) + srow;
      gload_lds16(g + (size_t)(b0 + r) * ld + kt + csw8, dst + (j << 12));
    }
  };

  union UU { u32x4 u; bf16x8 b; };
  auto ldvec = [&](const u16* base, int r, int c) -> bf16x8 {
    UU x;
    x.u = *(const u32x4*)(base + r * 64 + ((c ^ (r & 7)) << 3));
    return x.b;
  };

#pragma unroll
  for (int i = 0; i < 4; ++i) stage_ht(i);
  asm volatile("s_waitcnt vmcnt(0)" ::: "memory");
  __builtin_amdgcn_s_barrier();

  for (int t = 0; t < NT; ++t) {
    const u16* SA = lds + ((t & 1) << 15);
    const u16* SB = SA + 16384;
#pragma unroll
    for (int ph = 0; ph < 4; ++ph) {
      const int mh = ph >> 1, ks = ph & 1;
      const int c = (ks << 2) + lk;
      bf16x8 bb[4], aa[4];
#pragma unroll
      for (int ni = 0; ni < 4; ++ni)
        bb[ni] = ldvec(SB, (wc << 6) + (ni << 4) + lr, c);
#pragma unroll
      for (int mi = 0; mi < 4; ++mi)
        aa[mi] = ldvec(SA, (wr << 7) + (mh << 6) + (mi << 4) + lr, c);
      if (t + 1 < NT && ph < 2) {
        stage_ht(4 * (t + 1) + 2 * ph);
        stage_ht(4 * (t + 1) + 2 * ph + 1);
      }
      __builtin_amdgcn_s_barrier();
      __builtin_amdgcn_s_setprio(1);
#pragma unroll
      for (int mi = 0; mi < 4; ++mi)
#pragma unroll
        for (int ni = 0; ni < 4; ++ni)
          acc[(mh << 2) + mi][ni] = __builtin_amdgcn_mfma_f32_16x16x32_bf16(
              aa[mi], bb[ni], acc[(mh << 2) + mi][ni], 0, 0, 0);
      __builtin_amdgcn_s_setprio(0);
      if (ph == 3)
        asm volatile("s_waitcnt vmcnt(0)" ::: "memory");
      __builtin_amdgcn_s_barrier();
    }
  }

  float bs[4] = {0.f, 0.f, 0.f, 0.f};
  if (BIAS) {
#pragma unroll
    for (int ni = 0; ni < 4; ++ni)
      bs[ni] = bias[col0 + (wc << 6) + (ni << 4) + lr];
  }
#pragma unroll
  for (int mi = 0; mi < 8; ++mi) {
#pragma unroll
    for (int ni = 0; ni < 4; ++ni) {
#pragma unroll
      for (int r = 0; r < 4; ++r) {
        int row = row0 + (wr << 7) + (mi << 4) + (lk << 2) + r;
        int col = col0 + (wc << 6) + (ni << 4) + lr;
        float v = acc[mi][ni][r] + bs[ni];
        if (RELU) v = fmaxf(v, 0.f);
        if (F32OUT) outf[outoff + (size_t)row * N + col] = v;
        if (BF16OUT) outb[outoff + (size_t)row * N + col] = f2bf(v);
      }
    }
  }
}

// ---------------- V transpose: QKV[(b,s)][2048+h*64+d] -> Vt[bh][d][s] ----------------
__global__ __launch_bounds__(256) void k_vt(const u16* __restrict__ QKV,
                                            u16* __restrict__ vt) {
  __shared__ u16 T[64 * 64];
  const int tid = threadIdx.x;
  const int s0 = blockIdx.x * 64;
  const int bh = blockIdx.y;
  const int b = bh >> 4, h = bh & 15;
#pragma unroll
  for (int p = 0; p < 2; ++p) {
    int id = p * 256 + tid;
    int r = id >> 3, c = id & 7;
    u32x4 v = *(const u32x4*)(QKV + (size_t)(b * S_ + s0 + r) * 3072 + 2048 + h * 64 + c * 8);
    int sw = (r ^ (r >> 3)) & 7;
    *(u32x4*)(T + r * 64 + ((c ^ sw) << 3)) = v;
  }
  __syncthreads();
#pragma unroll
  for (int p = 0; p < 2; ++p) {
    int id = p * 256 + tid;
    int d = id >> 3, cs = id & 7;
    u16 tmp[8];
#pragma unroll
    for (int k = 0; k < 8; ++k) {
      int r = cs * 8 + k;
      int sw = (r ^ (r >> 3)) & 7;
      tmp[k] = T[r * 64 + ((((d >> 3) ^ sw)) << 3) + (d & 7)];
    }
    *(u32x4*)(vt + ((size_t)bh * 64 + d) * 2048 + s0 + cs * 8) = *(const u32x4*)tmp;
  }
}

// ======== MFMA flash attention, swapped-QK^T 32x32 (round-7 proven body) ========
// + T13 defer-max (THR=8, skip O-rescale when wave max grew <= 8)
// + T5 setprio(1) around the MFMA clusters
__global__ __launch_bounds__(256, 3) void k_attn_mfma(const u16* __restrict__ QKV,
                                                      const u16* __restrict__ Vt,
                                                      u16* __restrict__ mid) {
  __shared__ u16 lds[9216];
  u16* Ks = lds;
  u16* Vs = lds + 4096;
  const int tid = threadIdx.x, lane = tid & 63, wid = tid >> 6;
  const int lq = lane & 31, lh = lane >> 5;
  const int qb = (S_ / 128 - 1) - blockIdx.x;  // heavy blocks first
  const int bh = blockIdx.y;
  const int b = bh >> 4, h = bh & 15;
  const int q0w = qb * 128 + wid * 32;
  const int qg = q0w + lq;

  union U { u32x4 u; bf16x8 b; };
  U qf[4];
#pragma unroll
  for (int ks = 0; ks < 4; ++ks) {
    const size_t off = (size_t)(b * S_ + qg) * 3072 + h * HD + ks * 16 + lh * 8;
    u32x4 u = *(const u32x4*)(QKV + off);
    u32x4 s;
#pragma unroll
    for (int t = 0; t < 4; ++t) {
      u32 lo = (u32)f2bf(bflo(u[t]) * 0.125f);
      u32 hi = (u32)f2bf(bfhi(u[t]) * 0.125f);
      s[t] = lo | (hi << 16);
    }
    qf[ks].u = s;
  }

  float m = -1e30f, l = 0.f;
  f32x16 acc[2];
#pragma unroll
  for (int mo = 0; mo < 2; ++mo)
#pragma unroll
    for (int r = 0; r < 16; ++r) acc[mo][r] = 0.f;

  const int nt = qb * 2 + 2;
  for (int kv = 0; kv < nt; ++kv) {
    const int kv0 = kv * 64;
    __syncthreads();
#pragma unroll
    for (int p = 0; p < 2; ++p) {
      int id = p * 256 + tid;
      int r = id >> 3, c = id & 7;
      u32x4 ku = *(const u32x4*)(QKV + (size_t)(b * S_ + kv0 + r) * 3072 + 1024 + h * 64 + c * 8);
      *(u32x4*)(Ks + r * 64 + ((c ^ (r & 7)) << 3)) = ku;
      u32x4 vu = *(const u32x4*)(Vt + ((size_t)bh * 64 + r) * 2048 + kv0 + c * 8);
      *(u32x4*)(Vs + r * 64 + ((c ^ (r & 7)) << 3)) = vu;
    }
    __syncthreads();

    if (kv0 > q0w + 31) continue;

    // ---- S^T = K @ Q^T ----
    f32x16 sf[2];
#pragma unroll
    for (int nf = 0; nf < 2; ++nf)
#pragma unroll
      for (int r = 0; r < 16; ++r) sf[nf][r] = 0.f;
    __builtin_amdgcn_s_setprio(1);
#pragma unroll
    for (int ks = 0; ks < 4; ++ks) {
#pragma unroll
      for (int nf = 0; nf < 2; ++nf) {
        int r = nf * 32 + lq;
        int c = ks * 2 + lh;
        U kf;
        kf.u = *(const u32x4*)(Ks + r * 64 + ((c ^ (r & 7)) << 3));
        sf[nf] = __builtin_amdgcn_mfma_f32_32x32x16_bf16(kf.b, qf[ks].b, sf[nf], 0, 0, 0);
      }
    }
    __builtin_amdgcn_s_setprio(0);

    // ---- causal mask (boundary tiles) ----
    if (kv0 + 63 > q0w) {
#pragma unroll
      for (int nf = 0; nf < 2; ++nf)
#pragma unroll
        for (int r = 0; r < 16; ++r) {
          int kvg = kv0 + nf * 32 + (r & 3) + 8 * (r >> 2) + 4 * lh;
          if (kvg > qg) sf[nf][r] = -1e30f;
        }
    }

    // ---- in-register online softmax with defer-max (THR=8) ----
    float tm = sf[0][0];
#pragma unroll
    for (int r = 1; r < 16; ++r) tm = fmaxf(tm, sf[0][r]);
#pragma unroll
    for (int r = 0; r < 16; ++r) tm = fmaxf(tm, sf[1][r]);
    tm = fmaxf(tm, __shfl_xor(tm, 32));
    if (__any(tm - m > 8.f)) {  // rescale only on real max growth
      const float mn = fmaxf(m, tm);
      const float corr = __expf(m - mn);
      m = mn;
      l *= corr;
#pragma unroll
      for (int mo = 0; mo < 2; ++mo)
#pragma unroll
        for (int r = 0; r < 16; ++r) acc[mo][r] *= corr;
    }
    float rs = 0.f;
#pragma unroll
    for (int nf = 0; nf < 2; ++nf)
#pragma unroll
      for (int r = 0; r < 16; ++r) {
        float p = __expf(sf[nf][r] - m);  // bounded by e^8
        sf[nf][r] = p;
        rs += p;
      }
    rs += __shfl_xor(rs, 32);
    l += rs;

    // ---- P -> packed bf16, O^T += V^T @ P^T ----
    u32 q32[2][8];
#pragma unroll
    for (int nf = 0; nf < 2; ++nf)
#pragma unroll
      for (int i = 0; i < 8; ++i)
        asm("v_cvt_pk_bf16_f32 %0, %1, %2"
            : "=v"(q32[nf][i]) : "v"(sf[nf][2 * i]), "v"(sf[nf][2 * i + 1]));

    __builtin_amdgcn_s_setprio(1);
#pragma unroll
    for (int s = 0; s < 4; ++s) {
      const int nfp = s >> 1, sg = s & 1;
      u32 x = q32[nfp][4 * sg + 0];
      u32 y = q32[nfp][4 * sg + 1];
      u32 z = q32[nfp][4 * sg + 2];
      u32 w = q32[nfp][4 * sg + 3];
      asm("v_permlane32_swap_b32 %0, %1" : "+v"(x), "+v"(z));
      asm("v_permlane32_swap_b32 %0, %1" : "+v"(y), "+v"(w));
      U pb;
      pb.u = (u32x4){x, y, z, w};
#pragma unroll
      for (int mo = 0; mo < 2; ++mo) {
        int r = mo * 32 + lq;
        int c = s * 2 + lh;
        U vv;
        vv.u = *(const u32x4*)(Vs + r * 64 + ((c ^ (r & 7)) << 3));
        acc[mo] = __builtin_amdgcn_mfma_f32_32x32x16_bf16(vv.b, pb.b, acc[mo], 0, 0, 0);
      }
    }
    __builtin_amdgcn_s_setprio(0);
  }

  // ---- epilogue: O^T/l -> LDS transpose -> coalesced store ----
  __syncthreads();
  u16* Ow = lds + wid * (32 * 72);
  const float inv = 1.f / l;
#pragma unroll
  for (int mo = 0; mo < 2; ++mo)
#pragma unroll
    for (int r = 0; r < 16; ++r) {
      int d = mo * 32 + (r & 3) + 8 * (r >> 2) + 4 * lh;
      Ow[lq * 72 + d] = f2bf(acc[mo][r] * inv);
    }
  __asm__ volatile("" ::: "memory");
#pragma unroll
  for (int r4 = 0; r4 < 4; ++r4) {
    int ql = r4 * 8 + (lane >> 3);
    int c = lane & 7;
    u32x4 v = *(const u32x4*)(Ow + ql * 72 + c * 8);
    *(u32x4*)(mid + (size_t)(b * S_ + q0w + ql) * H_ + h * HD + c * 8) = v;
  }
}

// ------- fused residual + split-K reduce + LayerNorm -------
template<int BF16OUT, int NZ>
__global__ __launch_bounds__(256) void k_lnr(const float* __restrict__ a,
                                             const u16* __restrict__ P,
                                             const float* __restrict__ bd,
                                             const float* __restrict__ g,
                                             const float* __restrict__ bb,
                                             float* __restrict__ outf,
                                             u16* __restrict__ outb) {
  __shared__ float red[8];
  const int row = blockIdx.x, tid = threadIdx.x;
  const size_t base = (size_t)row * H_ + tid * 4;
  f32x4 t = *(const f32x4*)(a + base);
  f32x4 vb = *(const f32x4*)(bd + tid * 4);
  t += vb;
#pragma unroll
  for (int z = 0; z < NZ; ++z) {
    u16x4 p = *(const u16x4*)(P + (size_t)z * ((size_t)B_ * S_ * H_) + base);
#pragma unroll
    for (int e = 0; e < 4; ++e) t[e] += __uint_as_float((u32)p[e] << 16);
  }
  float sum = t[0] + t[1] + t[2] + t[3];
#pragma unroll
  for (int msk = 32; msk >= 1; msk >>= 1) sum += __shfl_xor(sum, msk, 64);
  if ((tid & 63) == 0) red[tid >> 6] = sum;
  __syncthreads();
  float mu = (red[0] + red[1] + red[2] + red[3]) * (1.f / H_);
  f32x4 d = t - mu;
  float sq = d[0] * d[0] + d[1] * d[1] + d[2] * d[2] + d[3] * d[3];
#pragma unroll
  for (int msk = 32; msk >= 1; msk >>= 1) sq += __shfl_xor(sq, msk, 64);
  if ((tid & 63) == 0) red[4 + (tid >> 6)] = sq;
  __syncthreads();
  float var = (red[4] + red[5] + red[6] + red[7]) * (1.f / H_);
  float rs = rsqrtf(var + LN_EPS);
  f32x4 gg = *(const f32x4*)(g + tid * 4);
  f32x4 bv = *(const f32x4*)(bb + tid * 4);
  f32x4 o = d * rs * gg + bv;
  *(f32x4*)(outf + base) = o;
  if (BF16OUT) {
    u16x4 ob = { f2bf(o[0]), f2bf(o[1]), f2bf(o[2]), f2bf(o[3]) };
    *(u16x4*)(outb + base) = ob;
  }
}

// ---------------- host launcher ----------------
extern "C" void kernel_launch(void* const* d_in, const int* in_sizes, int n_in,
                              void* d_out, int out_size, void* d_ws, size_t ws_size,
                              hipStream_t stream) {
  const float* X   = (const float*)d_in[0];
  const float* Wq  = (const float*)d_in[1];
  const float* bq  = (const float*)d_in[2];
  const float* Wk  = (const float*)d_in[3];
  const float* bk  = (const float*)d_in[4];
  const float* Wv  = (const float*)d_in[5];
  const float* bv  = (const float*)d_in[6];
  const float* Wo  = (const float*)d_in[7];
  const float* bo  = (const float*)d_in[8];
  const float* g1  = (const float*)d_in[9];
  const float* b1  = (const float*)d_in[10];
  const float* Wup = (const float*)d_in[11];
  const float* bup = (const float*)d_in[12];
  const float* Wdn = (const float*)d_in[13];
  const float* bdn = (const float*)d_in[14];
  const float* g2  = (const float*)d_in[15];
  const float* b2  = (const float*)d_in[16];
  float* out = (float*)d_out;

  const size_t MS = (size_t)B_ * S_;   // 4096
  const size_t nX = MS * H_;           // 4,194,304

  char* ws = (char*)d_ws;
  size_t off = 0;
  auto alloc = [&](size_t bytes) {
    char* p = ws + off;
    off += (bytes + 255) & ~(size_t)255;
    return p;
  };
  u16* Xb    = (u16*)alloc(nX * 2);                    // 8MB   (h alias start)
  u16* Wqkv  = (u16*)alloc((size_t)3 * H_ * H_ * 2);   // 6MB
  u16* Wob   = (u16*)alloc((size_t)H_ * H_ * 2);       // 2MB   (h = 16MB over these 3)
  u16* Wupb  = (u16*)alloc((size_t)4 * H_ * H_ * 2);   // 8MB
  u16* Wdnb  = (u16*)alloc((size_t)4 * H_ * H_ * 2);   // 8MB
  float* bqkv = (float*)alloc(3 * H_ * 4);             // 12KB
  u16* QKVb  = (u16*)alloc(nX * 3 * 2);                // 24MB  (upb alias start)
  u16* midb  = (u16*)alloc(nX * 2);                    // 8MB
  u16* Pbuf  = (u16*)alloc(nX * 4 * 2);                // 32MB: vtb / WoP / hb / P
  // aliases (producer strictly after old consumers in stream order):
  float* h   = (float*)Xb;        // 16MB f32 (Xb+Wqkv+Wob dead after QKV/Wo GEMMs)
  u16* upb   = QKVb;              // 32MB (QKVb dead after attn, midb after Wo)
  u16* vtb   = Pbuf;              // 8MB  (dead after attn)
  u16* WoP   = Pbuf;              // 2 x 8MB Wo split-K partials (over dead vtb)
  u16* hb    = Pbuf + nX * 2;     // 8MB bf16 h at [16,24)MB (WoP ends at 16MB)
  u16* P     = Pbuf;              // 4 x 8MB down partials (WoP+hb dead by then)

  dim3 blk(256);

  // one fused conversion launch (dst = contiguous Xb|Wqkv|Wob|Wupb|Wdnb)
  k_cvt_all<<<dim3(16384), blk, 0, stream>>>(X, Wq, Wk, Wv, Wo, Wup, Wdn, Xb);
  k_pack3<<<dim3(12), blk, 0, stream>>>(bq, bk, bv, bqkv);

  // fused QKV projection [4096,3072]: grid 16*12 = 192
  k_gemm8<0, 0, 1, 1><<<dim3(16 * 12), dim3(512), 131072, stream>>>(
      Xb, Wqkv, bqkv, nullptr, QKVb, (int)MS, 3 * H_, H_, H_, H_, 16);

  k_vt<<<dim3(S_ / 64, B_ * NH), blk, 0, stream>>>(QKVb, vtb);

  // causal MFMA flash attention
  k_attn_mfma<<<dim3(S_ / 128, B_ * NH), blk, 0, stream>>>(QKVb, vtb, midb);

  // output projection split-K=2, bf16 partials: grid 16*4*2 = 128
  k_gemm8<0, 0, 1, 0><<<dim3(16 * 4 * 2), dim3(512), 131072, stream>>>(
      midb, Wob, nullptr, nullptr, WoP, (int)MS, H_, H_, H_, 512, 16);

  // LN1 + Wo-reduce: h = LN(X + sum WoP + bo), bf16 copy hb
  k_lnr<1, 2><<<dim3(MS), blk, 0, stream>>>(X, WoP, bo, g1, b1, h, hb);

  // MLP up [4096,4096] ReLU: grid 16*16 = 256
  k_gemm8<1, 0, 1, 1><<<dim3(16 * 16), dim3(512), 131072, stream>>>(
      hb, Wupb, bup, nullptr, upb, (int)MS, 4 * H_, H_, H_, H_, 16);

  // MLP down split-K=4, bf16 partials: grid 16*4*4 = 256
  k_gemm8<0, 0, 1, 0><<<dim3(16 * 4 * 4), dim3(512), 131072, stream>>>(
      upb, Wdnb, nullptr, nullptr, P, (int)MS, H_, 4 * H_, 4 * H_, H_, 16);

  // LN2 + down-reduce -> out
  k_lnr<0, 4><<<dim3(MS), blk, 0, stream>>>(h, P, bdn, g2, b2, out, nullptr);
}